// Round 8
// baseline (583.969 us; speedup 1.0000x reference)
//
#include <hip/hip_runtime.h>
#include <hip/hip_fp16.h>

#define NN 100000
#define NE 1600000
#define NF 64
#define DM 32
#define NG 64
#define NC 10
#define BN_EPS 1e-5f

#define BSHIFT 8
#define NBUCK ((NN + 255) >> 8)        // 391 buckets of 256 nodes
#define CHUNK 8192                     // edges per binning block
#define NCH ((NE + CHUNK - 1) / CHUNK) // 196

// ---- fp16 pack/unpack helpers (RNE) ----
__device__ __forceinline__ float2 up2(unsigned u) {
    __half2 h = __builtin_bit_cast(__half2, u);
    return __half22float2(h);
}
__device__ __forceinline__ unsigned pk2(float a, float b) {
    __half2 h = __floats2half2_rn(a, b);
    return __builtin_bit_cast(unsigned, h);
}

// ============ CSR build via bucket counting-sort ============
__global__ __launch_bounds__(256) void binA_k(const int* __restrict__ ei,
                                              int* __restrict__ bcnt) {
    __shared__ int h[NBUCK];
    for (int i = threadIdx.x; i < NBUCK; i += 256) h[i] = 0;
    __syncthreads();
    long long base = (long long)blockIdx.x * CHUNK;
    int n = (int)((NE - base < CHUNK) ? (NE - base) : CHUNK);
    for (int i = threadIdx.x; i < n; i += 256) {
        int d = ei[NE + base + i];
        atomicAdd(&h[d >> BSHIFT], 1);
    }
    __syncthreads();
    for (int i = threadIdx.x; i < NBUCK; i += 256)
        if (h[i]) atomicAdd(&bcnt[i], h[i]);
}

__global__ __launch_bounds__(512) void binB_k(const int* __restrict__ bcnt,
                                              int* __restrict__ bbase,
                                              int* __restrict__ bcur) {
    __shared__ int s[512];
    int t = threadIdx.x;
    int v = (t < NBUCK) ? bcnt[t] : 0;
    s[t] = v;
    __syncthreads();
    int acc = v;
    for (int off = 1; off < 512; off <<= 1) {
        int add = (t >= off) ? s[t - off] : 0;
        __syncthreads();
        acc += add;
        s[t] = acc;
        __syncthreads();
    }
    if (t < NBUCK) { bbase[t] = acc - v; bcur[t] = acc - v; }
    if (t == 0) bbase[NBUCK] = NE;
}

__global__ __launch_bounds__(256) void binC_k(const int* __restrict__ ei,
                                              int* __restrict__ bcur,
                                              unsigned* __restrict__ binned) {
    __shared__ int cnt[NBUCK];
    __shared__ int ofs[NBUCK];
    __shared__ int idx[NBUCK];
    for (int i = threadIdx.x; i < NBUCK; i += 256) { cnt[i] = 0; idx[i] = 0; }
    __syncthreads();
    long long base = (long long)blockIdx.x * CHUNK;
    int n = (int)((NE - base < CHUNK) ? (NE - base) : CHUNK);
    int d[CHUNK / 256];
#pragma unroll
    for (int k = 0; k < CHUNK / 256; k++) {
        int i = threadIdx.x + k * 256;
        int dd = (i < n) ? ei[NE + base + i] : -1;
        d[k] = dd;
        if (dd >= 0) atomicAdd(&cnt[dd >> BSHIFT], 1);
    }
    __syncthreads();
    for (int i = threadIdx.x; i < NBUCK; i += 256)
        if (cnt[i]) ofs[i] = atomicAdd(&bcur[i], cnt[i]);
    __syncthreads();
#pragma unroll
    for (int k = 0; k < CHUNK / 256; k++) {
        int i = threadIdx.x + k * 256;
        if (i < n) {
            unsigned src = (unsigned)ei[base + i];
            int b = d[k] >> BSHIFT;
            int l = atomicAdd(&idx[b], 1);
            binned[ofs[b] + l] = (src << 8) | (unsigned)(d[k] & 255);
        }
    }
}

__global__ __launch_bounds__(256) void binD_k(const unsigned* __restrict__ binned,
                                              const int* __restrict__ bbase,
                                              int* __restrict__ rowptr,
                                              int* __restrict__ csr) {
    __shared__ int cnt[256];
    __shared__ int cur[256];
    __shared__ int s[256];
    int b = blockIdx.x;
    int e0 = bbase[b], e1 = bbase[b + 1];
    int t = threadIdx.x;
    cnt[t] = 0;
    __syncthreads();
    for (int e = e0 + t; e < e1; e += 256) atomicAdd(&cnt[binned[e] & 255u], 1);
    __syncthreads();
    int v = cnt[t];
    s[t] = v;
    __syncthreads();
    int acc = v;
    for (int off = 1; off < 256; off <<= 1) {
        int add = (t >= off) ? s[t - off] : 0;
        __syncthreads();
        acc += add;
        s[t] = acc;
        __syncthreads();
    }
    int base = e0 + acc - v;
    int node = (b << BSHIFT) + t;
    if (node < NN) rowptr[node] = base;
    cur[t] = base;
    if (b == NBUCK - 1 && t == 0) rowptr[NN] = NE;
    __syncthreads();
    for (int e = e0 + t; e < e1; e += 256) {
        unsigned w = binned[e];
        int p = atomicAdd(&cur[w & 255u], 1);
        csr[p] = (int)(w >> 8);
    }
}

// ============ pre-pass layer 1: y = x @ W1a, 4 lanes/node (8 outputs each) ============
__global__ __launch_bounds__(256) void pre1_k(const float* __restrict__ x,
                                              const float* __restrict__ wa,
                                              float* __restrict__ y,
                                              unsigned* __restrict__ yhf,
                                              float* __restrict__ zbuf) {
    __shared__ float sWa[64 * 32];
    int tid = threadIdx.x;
    if (blockIdx.x == 0) {
        for (int i = tid; i < 5 * 64 + NG * 32; i += 256) zbuf[i] = 0.f;
    }
    for (int i = tid; i < 64 * 32; i += 256) sWa[i] = wa[i];
    __syncthreads();
    int l = tid & 3;
    int node = blockIdx.x * 64 + (tid >> 2);
    if (node >= NN) return;
    float t[8];
#pragma unroll
    for (int j = 0; j < 8; j++) t[j] = 0.f;
    const float4* xr = reinterpret_cast<const float4*>(x + (long long)node * 64);
    const float4* w4 = reinterpret_cast<const float4*>(sWa);
#pragma unroll
    for (int k4 = 0; k4 < 16; k4++) {
        float4 xv = xr[k4];
        float av[4] = {xv.x, xv.y, xv.z, xv.w};
#pragma unroll
        for (int i = 0; i < 4; i++) {
            float a = av[i];
            float4 w0 = w4[(k4 * 4 + i) * 8 + 2 * l];
            float4 w1 = w4[(k4 * 4 + i) * 8 + 2 * l + 1];
            t[0] += a * w0.x; t[1] += a * w0.y; t[2] += a * w0.z; t[3] += a * w0.w;
            t[4] += a * w1.x; t[5] += a * w1.y; t[6] += a * w1.z; t[7] += a * w1.w;
        }
    }
    float4* yr = reinterpret_cast<float4*>(y + (long long)node * 32 + l * 8);
    float4 o0, o1;
    o0.x = t[0]; o0.y = t[1]; o0.z = t[2]; o0.w = t[3];
    o1.x = t[4]; o1.y = t[5]; o1.z = t[6]; o1.w = t[7];
    yr[0] = o0; yr[1] = o1;
    uint4 p;
    p.x = pk2(t[0], t[1]); p.y = pk2(t[2], t[3]);
    p.z = pk2(t[4], t[5]); p.w = pk2(t[6], t[7]);
    reinterpret_cast<uint4*>(yhf)[(long long)node * 4 + l] = p;
}

// ============ fp16 gather: 4 lanes/node, 16B/lane, unroll x4, fp32 accum ============
template <bool BN>
__global__ __launch_bounds__(256) void gatherH_k(const unsigned* __restrict__ thf,
                                                 const int* __restrict__ rowptr,
                                                 const int* __restrict__ csr,
                                                 float* __restrict__ agg,
                                                 const float* __restrict__ st,
                                                 const float* __restrict__ gamma,
                                                 const float* __restrict__ beta) {
    int tid = threadIdx.x;
    int node = blockIdx.x * 64 + (tid >> 2);
    int l = tid & 3;                         // feats l*8 .. l*8+7
    if (node >= NN) return;
    float sc[8], sh[8];
    if (BN) {
        const float invn = 1.0f / NN;
#pragma unroll
        for (int c = 0; c < 8; c++) {
            int f = 8 * l + c;
            float mu = st[f] * invn;
            float var = st[32 + f] * invn - mu * mu;
            float scale = rsqrtf(var + BN_EPS) * gamma[f];
            sc[c] = scale;
            sh[c] = beta[f] - mu * scale;
        }
    }
    int s = rowptr[node], e = rowptr[node + 1];
    const uint4* t4 = reinterpret_cast<const uint4*>(thf);
    float a[8];
#pragma unroll
    for (int c = 0; c < 8; c++) a[c] = 0.f;
    int i = s;
    for (; i + 4 <= e; i += 4) {
        int s0 = csr[i], s1 = csr[i + 1], s2 = csr[i + 2], s3 = csr[i + 3];
        uint4 w0 = t4[(long long)s0 * 4 + l];
        uint4 w1 = t4[(long long)s1 * 4 + l];
        uint4 w2 = t4[(long long)s2 * 4 + l];
        uint4 w3 = t4[(long long)s3 * 4 + l];
        float2 p;
        p = up2(w0.x); a[0] += p.x; a[1] += p.y;
        p = up2(w0.y); a[2] += p.x; a[3] += p.y;
        p = up2(w0.z); a[4] += p.x; a[5] += p.y;
        p = up2(w0.w); a[6] += p.x; a[7] += p.y;
        p = up2(w1.x); a[0] += p.x; a[1] += p.y;
        p = up2(w1.y); a[2] += p.x; a[3] += p.y;
        p = up2(w1.z); a[4] += p.x; a[5] += p.y;
        p = up2(w1.w); a[6] += p.x; a[7] += p.y;
        p = up2(w2.x); a[0] += p.x; a[1] += p.y;
        p = up2(w2.y); a[2] += p.x; a[3] += p.y;
        p = up2(w2.z); a[4] += p.x; a[5] += p.y;
        p = up2(w2.w); a[6] += p.x; a[7] += p.y;
        p = up2(w3.x); a[0] += p.x; a[1] += p.y;
        p = up2(w3.y); a[2] += p.x; a[3] += p.y;
        p = up2(w3.z); a[4] += p.x; a[5] += p.y;
        p = up2(w3.w); a[6] += p.x; a[7] += p.y;
    }
    for (; i < e; i++) {
        uint4 w = t4[(long long)csr[i] * 4 + l];
        float2 p;
        p = up2(w.x); a[0] += p.x; a[1] += p.y;
        p = up2(w.y); a[2] += p.x; a[3] += p.y;
        p = up2(w.z); a[4] += p.x; a[5] += p.y;
        p = up2(w.w); a[6] += p.x; a[7] += p.y;
    }
    if (BN) {
        float deg = (float)(e - s);
#pragma unroll
        for (int c = 0; c < 8; c++) a[c] = a[c] * sc[c] + deg * sh[c];
    }
    float4* ar = reinterpret_cast<float4*>(agg + (long long)node * 32 + l * 8);
    float4 o0, o1;
    o0.x = a[0]; o0.y = a[1]; o0.z = a[2]; o0.w = a[3];
    o1.x = a[4]; o1.y = a[5]; o1.z = a[6]; o1.w = a[7];
    ar[0] = o0;
    ar[1] = o1;
}

// ============ layer 1 tail: 4 lanes/node. t=relu(y+agg+ba) slice; r=t@Wb via shfl; stats ============
__global__ __launch_bounds__(256) void mlp1b_k(const float* __restrict__ y,
                                               const float* __restrict__ agg,
                                               const float* __restrict__ ba,
                                               const float* __restrict__ wb,
                                               const float* __restrict__ bb,
                                               float* __restrict__ out,
                                               unsigned* __restrict__ outhf,
                                               float* __restrict__ stats) {
    __shared__ float sWb[32 * 32];
    __shared__ float sBa[32], sBb[32];
    __shared__ float sSum[4 * 32], sSq[4 * 32];
    int tid = threadIdx.x;
    for (int i = tid; i < 32 * 32; i += 256) sWb[i] = wb[i];
    if (tid < 32) { sBa[tid] = ba[tid]; sBb[tid] = bb[tid]; }
    __syncthreads();

    int l = tid & 3;
    int node = blockIdx.x * 64 + (tid >> 2);
    bool act = node < NN;
    float t[8];
    if (act) {
        const float4* yr = reinterpret_cast<const float4*>(y + (long long)node * 32 + l * 8);
        const float4* ar = reinterpret_cast<const float4*>(agg + (long long)node * 32 + l * 8);
        float4 y0 = yr[0], y1 = yr[1], a0 = ar[0], a1 = ar[1];
        t[0] = fmaxf(y0.x + a0.x + sBa[l * 8 + 0], 0.f);
        t[1] = fmaxf(y0.y + a0.y + sBa[l * 8 + 1], 0.f);
        t[2] = fmaxf(y0.z + a0.z + sBa[l * 8 + 2], 0.f);
        t[3] = fmaxf(y0.w + a0.w + sBa[l * 8 + 3], 0.f);
        t[4] = fmaxf(y1.x + a1.x + sBa[l * 8 + 4], 0.f);
        t[5] = fmaxf(y1.y + a1.y + sBa[l * 8 + 5], 0.f);
        t[6] = fmaxf(y1.z + a1.z + sBa[l * 8 + 6], 0.f);
        t[7] = fmaxf(y1.w + a1.w + sBa[l * 8 + 7], 0.f);
    } else {
#pragma unroll
        for (int j = 0; j < 8; j++) t[j] = 0.f;
    }

    float r[8];
#pragma unroll
    for (int j = 0; j < 8; j++) r[j] = sBb[l * 8 + j];
    const float4* v4 = reinterpret_cast<const float4*>(sWb);
#pragma unroll
    for (int k = 0; k < 32; k++) {
        float a = __shfl(t[k & 7], k >> 3, 4);
        float4 w0 = v4[k * 8 + 2 * l];
        float4 w1 = v4[k * 8 + 2 * l + 1];
        r[0] += a * w0.x; r[1] += a * w0.y; r[2] += a * w0.z; r[3] += a * w0.w;
        r[4] += a * w1.x; r[5] += a * w1.y; r[6] += a * w1.z; r[7] += a * w1.w;
    }
#pragma unroll
    for (int j = 0; j < 8; j++) r[j] = fmaxf(r[j], 0.f);

    if (act) {
        float4* orow = reinterpret_cast<float4*>(out + (long long)node * 32 + l * 8);
        float4 o0, o1;
        o0.x = r[0]; o0.y = r[1]; o0.z = r[2]; o0.w = r[3];
        o1.x = r[4]; o1.y = r[5]; o1.z = r[6]; o1.w = r[7];
        orow[0] = o0; orow[1] = o1;
        uint4 p;
        p.x = pk2(r[0], r[1]); p.y = pk2(r[2], r[3]);
        p.z = pk2(r[4], r[5]); p.w = pk2(r[6], r[7]);
        reinterpret_cast<uint4*>(outhf)[(long long)node * 4 + l] = p;
    } else {
#pragma unroll
        for (int j = 0; j < 8; j++) r[j] = 0.f;
    }

    // stats: stride-4 reduce over 16 nodes in wave -> lanes 0..3 hold 8 feats each
    int lane = tid & 63, wid = tid >> 6;
#pragma unroll
    for (int j = 0; j < 8; j++) {
        float v = r[j], v2 = v * v;
        v += __shfl_down(v, 32, 64); v2 += __shfl_down(v2, 32, 64);
        v += __shfl_down(v, 16, 64); v2 += __shfl_down(v2, 16, 64);
        v += __shfl_down(v, 8, 64);  v2 += __shfl_down(v2, 8, 64);
        v += __shfl_down(v, 4, 64);  v2 += __shfl_down(v2, 4, 64);
        if (lane < 4) { sSum[wid * 32 + lane * 8 + j] = v; sSq[wid * 32 + lane * 8 + j] = v2; }
    }
    __syncthreads();
    if (tid < 32) {
        float a = sSum[tid] + sSum[32 + tid] + sSum[64 + tid] + sSum[96 + tid];
        float b = sSq[tid] + sSq[32 + tid] + sSq[64 + tid] + sSq[96 + tid];
        atomicAdd(&stats[tid], a);
        atomicAdd(&stats[32 + tid], b);
    }
}

// ============ layers 2-5 MLP, 4 lanes/node, fused input BN, in-place h + fp16 copy ============
__global__ __launch_bounds__(256) void mlp32_bn_k(float* __restrict__ h,
                                                  unsigned* __restrict__ hhf,
                                                  const float* __restrict__ agg,
                                                  const float* __restrict__ wa,
                                                  const float* __restrict__ ba,
                                                  const float* __restrict__ wb,
                                                  const float* __restrict__ bb,
                                                  const float* __restrict__ st,
                                                  const float* __restrict__ gamma,
                                                  const float* __restrict__ beta,
                                                  float* __restrict__ statsOut) {
    __shared__ float sWa[32 * 32];
    __shared__ float sWb[32 * 32];
    __shared__ float sBa[32], sBb[32];
    __shared__ float sSc[32], sSh[32];
    __shared__ float sSum[4 * 32], sSq[4 * 32];
    int tid = threadIdx.x;
    for (int i = tid; i < 32 * 32; i += 256) { sWa[i] = wa[i]; sWb[i] = wb[i]; }
    if (tid < 32) {
        sBa[tid] = ba[tid]; sBb[tid] = bb[tid];
        const float invn = 1.0f / NN;
        float mu = st[tid] * invn;
        float var = st[32 + tid] * invn - mu * mu;
        float scale = rsqrtf(var + BN_EPS) * gamma[tid];
        sSc[tid] = scale;
        sSh[tid] = beta[tid] - mu * scale;
    }
    __syncthreads();

    int l = tid & 3;
    int node = blockIdx.x * 64 + (tid >> 2);
    bool act = node < NN;
    float t[8];
    const float4* w4a = reinterpret_cast<const float4*>(sWa);
    if (act) {
        // full BN'd input row in registers
        float a[32];
        const float4* hr = reinterpret_cast<const float4*>(h + (long long)node * 32);
        const float4* ar = reinterpret_cast<const float4*>(agg + (long long)node * 32);
#pragma unroll
        for (int k4 = 0; k4 < 8; k4++) {
            float4 xv = hr[k4];
            float4 av = ar[k4];
            a[k4 * 4 + 0] = xv.x * sSc[k4 * 4 + 0] + sSh[k4 * 4 + 0] + av.x;
            a[k4 * 4 + 1] = xv.y * sSc[k4 * 4 + 1] + sSh[k4 * 4 + 1] + av.y;
            a[k4 * 4 + 2] = xv.z * sSc[k4 * 4 + 2] + sSh[k4 * 4 + 2] + av.z;
            a[k4 * 4 + 3] = xv.w * sSc[k4 * 4 + 3] + sSh[k4 * 4 + 3] + av.w;
        }
#pragma unroll
        for (int j = 0; j < 8; j++) t[j] = sBa[l * 8 + j];
#pragma unroll
        for (int k = 0; k < 32; k++) {
            float av = a[k];
            float4 w0 = w4a[k * 8 + 2 * l];
            float4 w1 = w4a[k * 8 + 2 * l + 1];
            t[0] += av * w0.x; t[1] += av * w0.y; t[2] += av * w0.z; t[3] += av * w0.w;
            t[4] += av * w1.x; t[5] += av * w1.y; t[6] += av * w1.z; t[7] += av * w1.w;
        }
#pragma unroll
        for (int j = 0; j < 8; j++) t[j] = fmaxf(t[j], 0.f);
    } else {
#pragma unroll
        for (int j = 0; j < 8; j++) t[j] = 0.f;
    }

    float r[8];
#pragma unroll
    for (int j = 0; j < 8; j++) r[j] = sBb[l * 8 + j];
    const float4* v4 = reinterpret_cast<const float4*>(sWb);
#pragma unroll
    for (int k = 0; k < 32; k++) {
        float a = __shfl(t[k & 7], k >> 3, 4);
        float4 w0 = v4[k * 8 + 2 * l];
        float4 w1 = v4[k * 8 + 2 * l + 1];
        r[0] += a * w0.x; r[1] += a * w0.y; r[2] += a * w0.z; r[3] += a * w0.w;
        r[4] += a * w1.x; r[5] += a * w1.y; r[6] += a * w1.z; r[7] += a * w1.w;
    }
#pragma unroll
    for (int j = 0; j < 8; j++) r[j] = fmaxf(r[j], 0.f);

    if (act) {
        float4* orow = reinterpret_cast<float4*>(h + (long long)node * 32 + l * 8);
        float4 o0, o1;
        o0.x = r[0]; o0.y = r[1]; o0.z = r[2]; o0.w = r[3];
        o1.x = r[4]; o1.y = r[5]; o1.z = r[6]; o1.w = r[7];
        orow[0] = o0; orow[1] = o1;
        uint4 p;
        p.x = pk2(r[0], r[1]); p.y = pk2(r[2], r[3]);
        p.z = pk2(r[4], r[5]); p.w = pk2(r[6], r[7]);
        reinterpret_cast<uint4*>(hhf)[(long long)node * 4 + l] = p;
    } else {
#pragma unroll
        for (int j = 0; j < 8; j++) r[j] = 0.f;
    }

    int lane = tid & 63, wid = tid >> 6;
#pragma unroll
    for (int j = 0; j < 8; j++) {
        float v = r[j], v2 = v * v;
        v += __shfl_down(v, 32, 64); v2 += __shfl_down(v2, 32, 64);
        v += __shfl_down(v, 16, 64); v2 += __shfl_down(v2, 16, 64);
        v += __shfl_down(v, 8, 64);  v2 += __shfl_down(v2, 8, 64);
        v += __shfl_down(v, 4, 64);  v2 += __shfl_down(v2, 4, 64);
        if (lane < 4) { sSum[wid * 32 + lane * 8 + j] = v; sSq[wid * 32 + lane * 8 + j] = v2; }
    }
    __syncthreads();
    if (tid < 32) {
        float a = sSum[tid] + sSum[32 + tid] + sSum[64 + tid] + sSum[96 + tid];
        float b = sSq[tid] + sSq[32 + tid] + sSq[64 + tid] + sSq[96 + tid];
        atomicAdd(&statsOut[tid], a);
        atomicAdd(&statsOut[32 + tid], b);
    }
}

// ============ pool with fused BN of layer 5, privatized atomics ============
#define POOL_NPB 512
__global__ __launch_bounds__(256) void pool_bn_k(const float* __restrict__ h,
                                                 const int* __restrict__ batch,
                                                 const float* __restrict__ st,
                                                 const float* __restrict__ gamma,
                                                 const float* __restrict__ beta,
                                                 float* __restrict__ pooled) {
    int tid = threadIdx.x;
    int f = tid & 31;
    int p = tid >> 5;
    int n0 = blockIdx.x * POOL_NPB + p * (POOL_NPB / 8);
    int n1 = n0 + POOL_NPB / 8;
    if (n1 > NN) n1 = NN;
    if (n0 >= NN) return;
    const float invn = 1.0f / NN;
    float mu = st[f] * invn;
    float var = st[32 + f] * invn - mu * mu;
    float sc = rsqrtf(var + BN_EPS) * gamma[f];
    float sh = beta[f] - mu * sc;
    float acc = 0.f;
    int cur = batch[n0];
    for (int n = n0; n < n1; n++) {
        int g = batch[n];
        if (g != cur) {
            atomicAdd(&pooled[cur * 32 + f], acc);
            cur = g;
            acc = 0.f;
        }
        acc += h[(long long)n * 32 + f] * sc + sh;
    }
    atomicAdd(&pooled[cur * 32 + f], acc);
}

// ============ final FCs ============
__global__ __launch_bounds__(64) void final_k(const float* __restrict__ pooled,
                                              const float* __restrict__ w1,
                                              const float* __restrict__ b1,
                                              const float* __restrict__ w2,
                                              const float* __restrict__ b2,
                                              float* __restrict__ out) {
    int g = threadIdx.x;
    if (g >= NG) return;
    float t[32];
#pragma unroll
    for (int j = 0; j < 32; j++) t[j] = b1[j];
    for (int k = 0; k < 32; k++) {
        float a = pooled[g * 32 + k];
#pragma unroll
        for (int j = 0; j < 32; j++) t[j] += a * w1[k * 32 + j];
    }
#pragma unroll
    for (int j = 0; j < 32; j++) t[j] = fmaxf(t[j], 0.f);
    for (int c = 0; c < NC; c++) {
        float o = b2[c];
#pragma unroll
        for (int k = 0; k < 32; k++) o += t[k] * w2[k * NC + c];
        out[g * NC + c] = o;
    }
}

extern "C" void kernel_launch(void* const* d_in, const int* in_sizes, int n_in,
                              void* d_out, int out_size, void* d_ws, size_t ws_size,
                              hipStream_t stream) {
    const float* x = (const float*)d_in[0];
    const int* ei = (const int*)d_in[1];
    const int* batch = (const int*)d_in[2];
    const float* w1a = (const float*)d_in[3];
    const float* b1a = (const float*)d_in[4];
    const float* w1b = (const float*)d_in[5];
    const float* b1b = (const float*)d_in[6];
    const float* Wa = (const float*)d_in[7];
    const float* Ba = (const float*)d_in[8];
    const float* Wb = (const float*)d_in[9];
    const float* Bb = (const float*)d_in[10];
    const float* bn_gamma = (const float*)d_in[11];
    const float* bn_beta = (const float*)d_in[12];
    const float* fc1w = (const float*)d_in[13];
    const float* fc1b = (const float*)d_in[14];
    const float* fc2w = (const float*)d_in[15];
    const float* fc2b = (const float*)d_in[16];
    float* out = (float*)d_out;

    float* ws = (float*)d_ws;
    float* y = ws;                                    // NN*32 f32
    float* hb = y + (size_t)NN * 32;                  // NN*32 f32
    float* agg = hb + (size_t)NN * 32;                // NN*32 f32
    float* stats_all = agg + (size_t)NN * 32;         // 5*64
    float* pooled = stats_all + 5 * 64;               // NG*32
    unsigned* yhf = (unsigned*)(pooled + NG * 32);    // NN*16 uints (32 fp16/row)
    unsigned* hbhf = yhf + (size_t)NN * 16;           // NN*16 uints
    unsigned* binned = hbhf + (size_t)NN * 16;        // NE
    int* bcnt = (int*)(binned + NE);                  // NBUCK
    int* bbase = bcnt + NBUCK;                        // NBUCK+1
    int* bcur = bbase + NBUCK + 1;                    // NBUCK
    int* rowptr = bcur + NBUCK;                       // NN+1
    int* csr = rowptr + NN + 1;                       // NE

    const int nb4 = (NN + 63) / 64;   // 4 lanes/node kernels

    // ---- CSR build (bucketed, packed) ----
    hipMemsetAsync(bcnt, 0, NBUCK * sizeof(int), stream);
    binA_k<<<NCH, 256, 0, stream>>>(ei, bcnt);
    binB_k<<<1, 512, 0, stream>>>(bcnt, bbase, bcur);
    binC_k<<<NCH, 256, 0, stream>>>(ei, bcur, binned);
    binD_k<<<NBUCK, 256, 0, stream>>>(binned, bbase, rowptr, csr);

    // ---- layer 1: y = x@Wa (+fp16 copy, zeroes stats/pooled); gather fp16; tail MLP ----
    pre1_k<<<nb4, 256, 0, stream>>>(x, w1a, y, yhf, stats_all);
    gatherH_k<false><<<nb4, 256, 0, stream>>>(yhf, rowptr, csr, agg,
                                              nullptr, nullptr, nullptr);
    mlp1b_k<<<nb4, 256, 0, stream>>>(y, agg, b1a, w1b, b1b, hb, hbhf, stats_all);

    // ---- layers 2-5 (32 feat), BN fused into consumers, fp16 gather ----
    for (int i = 0; i < 4; i++) {
        const float* st = stats_all + i * 64;
        const float* g = bn_gamma + i * 32;
        const float* be = bn_beta + i * 32;
        gatherH_k<true><<<nb4, 256, 0, stream>>>(hbhf, rowptr, csr, agg, st, g, be);
        mlp32_bn_k<<<nb4, 256, 0, stream>>>(hb, hbhf, agg, Wa + i * 1024, Ba + i * 32,
                                            Wb + i * 1024, Bb + i * 32,
                                            st, g, be, stats_all + (i + 1) * 64);
    }

    // ---- pool (BN5 fused) + FCs ----
    pool_bn_k<<<(NN + POOL_NPB - 1) / POOL_NPB, 256, 0, stream>>>(
        hb, batch, stats_all + 4 * 64, bn_gamma + 4 * 32, bn_beta + 4 * 32, pooled);
    final_k<<<1, 64, 0, stream>>>(pooled, fc1w, fc1b, fc2w, fc2b, out);
}

// Round 9
// 528.301 us; speedup vs baseline: 1.1054x; 1.1054x over previous
//
#include <hip/hip_runtime.h>
#include <hip/hip_fp16.h>

#define NN 100000
#define NE 1600000
#define NF 64
#define DM 32
#define NG 64
#define NC 10
#define BN_EPS 1e-5f

#define BSHIFT 8
#define NBUCK ((NN + 255) >> 8)        // 391 buckets of 256 nodes
#define CHUNK 8192                     // edges per binning block
#define NCH ((NE + CHUNK - 1) / CHUNK) // 196

// ---- fp16 pack/unpack helpers (RNE) ----
__device__ __forceinline__ float2 up2(unsigned u) {
    __half2 h = __builtin_bit_cast(__half2, u);
    return __half22float2(h);
}
__device__ __forceinline__ unsigned pk2(float a, float b) {
    __half2 h = __floats2half2_rn(a, b);
    return __builtin_bit_cast(unsigned, h);
}

// ============ CSR build via bucket counting-sort ============
__global__ __launch_bounds__(256) void binA_k(const int* __restrict__ ei,
                                              int* __restrict__ bcnt) {
    __shared__ int h[NBUCK];
    for (int i = threadIdx.x; i < NBUCK; i += 256) h[i] = 0;
    __syncthreads();
    long long base = (long long)blockIdx.x * CHUNK;
    int n = (int)((NE - base < CHUNK) ? (NE - base) : CHUNK);
    for (int i = threadIdx.x; i < n; i += 256) {
        int d = ei[NE + base + i];
        atomicAdd(&h[d >> BSHIFT], 1);
    }
    __syncthreads();
    for (int i = threadIdx.x; i < NBUCK; i += 256)
        if (h[i]) atomicAdd(&bcnt[i], h[i]);
}

__global__ __launch_bounds__(512) void binB_k(const int* __restrict__ bcnt,
                                              int* __restrict__ bbase,
                                              int* __restrict__ bcur) {
    __shared__ int s[512];
    int t = threadIdx.x;
    int v = (t < NBUCK) ? bcnt[t] : 0;
    s[t] = v;
    __syncthreads();
    int acc = v;
    for (int off = 1; off < 512; off <<= 1) {
        int add = (t >= off) ? s[t - off] : 0;
        __syncthreads();
        acc += add;
        s[t] = acc;
        __syncthreads();
    }
    if (t < NBUCK) { bbase[t] = acc - v; bcur[t] = acc - v; }
    if (t == 0) bbase[NBUCK] = NE;
}

__global__ __launch_bounds__(256) void binC_k(const int* __restrict__ ei,
                                              int* __restrict__ bcur,
                                              unsigned* __restrict__ binned) {
    __shared__ int cnt[NBUCK];
    __shared__ int ofs[NBUCK];
    __shared__ int idx[NBUCK];
    for (int i = threadIdx.x; i < NBUCK; i += 256) { cnt[i] = 0; idx[i] = 0; }
    __syncthreads();
    long long base = (long long)blockIdx.x * CHUNK;
    int n = (int)((NE - base < CHUNK) ? (NE - base) : CHUNK);
    int d[CHUNK / 256];
#pragma unroll
    for (int k = 0; k < CHUNK / 256; k++) {
        int i = threadIdx.x + k * 256;
        int dd = (i < n) ? ei[NE + base + i] : -1;
        d[k] = dd;
        if (dd >= 0) atomicAdd(&cnt[dd >> BSHIFT], 1);
    }
    __syncthreads();
    for (int i = threadIdx.x; i < NBUCK; i += 256)
        if (cnt[i]) ofs[i] = atomicAdd(&bcur[i], cnt[i]);
    __syncthreads();
#pragma unroll
    for (int k = 0; k < CHUNK / 256; k++) {
        int i = threadIdx.x + k * 256;
        if (i < n) {
            unsigned src = (unsigned)ei[base + i];
            int b = d[k] >> BSHIFT;
            int l = atomicAdd(&idx[b], 1);
            binned[ofs[b] + l] = (src << 8) | (unsigned)(d[k] & 255);
        }
    }
}

__global__ __launch_bounds__(256) void binD_k(const unsigned* __restrict__ binned,
                                              const int* __restrict__ bbase,
                                              int* __restrict__ rowptr,
                                              int* __restrict__ csr) {
    __shared__ int cnt[256];
    __shared__ int cur[256];
    __shared__ int s[256];
    int b = blockIdx.x;
    int e0 = bbase[b], e1 = bbase[b + 1];
    int t = threadIdx.x;
    cnt[t] = 0;
    __syncthreads();
    for (int e = e0 + t; e < e1; e += 256) atomicAdd(&cnt[binned[e] & 255u], 1);
    __syncthreads();
    int v = cnt[t];
    s[t] = v;
    __syncthreads();
    int acc = v;
    for (int off = 1; off < 256; off <<= 1) {
        int add = (t >= off) ? s[t - off] : 0;
        __syncthreads();
        acc += add;
        s[t] = acc;
        __syncthreads();
    }
    int base = e0 + acc - v;
    int node = (b << BSHIFT) + t;
    if (node < NN) rowptr[node] = base;
    cur[t] = base;
    if (b == NBUCK - 1 && t == 0) rowptr[NN] = NE;
    __syncthreads();
    for (int e = e0 + t; e < e1; e += 256) {
        unsigned w = binned[e];
        int p = atomicAdd(&cur[w & 255u], 1);
        csr[p] = (int)(w >> 8);
    }
}

// ============ pre-pass layer 1: y = x @ W1a, 4 lanes/node; fp16 copy; zero accumulators ============
__global__ __launch_bounds__(256) void pre1_k(const float* __restrict__ x,
                                              const float* __restrict__ wa,
                                              float* __restrict__ y,
                                              unsigned* __restrict__ yhf,
                                              float* __restrict__ zbuf) {
    __shared__ float sWa[64 * 32];
    int tid = threadIdx.x;
    if (blockIdx.x == 0) {
        for (int i = tid; i < 5 * 64 + NG * 32; i += 256) zbuf[i] = 0.f;
    }
    for (int i = tid; i < 64 * 32; i += 256) sWa[i] = wa[i];
    __syncthreads();
    int l = tid & 3;
    int node = blockIdx.x * 64 + (tid >> 2);
    if (node >= NN) return;
    float t[8];
#pragma unroll
    for (int j = 0; j < 8; j++) t[j] = 0.f;
    const float4* xr = reinterpret_cast<const float4*>(x + (long long)node * 64);
    const float4* w4 = reinterpret_cast<const float4*>(sWa);
#pragma unroll
    for (int k4 = 0; k4 < 16; k4++) {
        float4 xv = xr[k4];
        float av[4] = {xv.x, xv.y, xv.z, xv.w};
#pragma unroll
        for (int i = 0; i < 4; i++) {
            float a = av[i];
            float4 w0 = w4[(k4 * 4 + i) * 8 + 2 * l];
            float4 w1 = w4[(k4 * 4 + i) * 8 + 2 * l + 1];
            t[0] += a * w0.x; t[1] += a * w0.y; t[2] += a * w0.z; t[3] += a * w0.w;
            t[4] += a * w1.x; t[5] += a * w1.y; t[6] += a * w1.z; t[7] += a * w1.w;
        }
    }
    float4* yr = reinterpret_cast<float4*>(y + (long long)node * 32 + l * 8);
    float4 o0, o1;
    o0.x = t[0]; o0.y = t[1]; o0.z = t[2]; o0.w = t[3];
    o1.x = t[4]; o1.y = t[5]; o1.z = t[6]; o1.w = t[7];
    yr[0] = o0; yr[1] = o1;
    uint4 p;
    p.x = pk2(t[0], t[1]); p.y = pk2(t[2], t[3]);
    p.z = pk2(t[4], t[5]); p.w = pk2(t[6], t[7]);
    reinterpret_cast<uint4*>(yhf)[(long long)node * 4 + l] = p;
}

// ============ fused gather + MLP + BN-stats, 4 lanes/node, 64 nodes/block ============
// MODE 0 (layer 1): t = relu(y_self + gathersum + ba); r = relu(t@Wb + bb)
// MODE 1 (layers 2-5): in = BN(h_self) + (sc*gathersum + deg*sh);
//                      t = relu(in@Wa + ba); r = relu(t@Wb + bb)
// Writes hOut (f32) + tblOut (fp16) rows; accumulates stats (sum, sumsq) of r.
// LDS stage buffer: feat-major [32][65-stride] so writes are 2-way (free) and
// reads are 16-address broadcast (conflict-free).
#define SSTR 65
template <int MODE>
__global__ __launch_bounds__(256) void fused_k(const float* __restrict__ selfRow,
                                               float* __restrict__ hOut,
                                               const unsigned* __restrict__ tblIn,
                                               unsigned* __restrict__ tblOut,
                                               const int* __restrict__ rowptr,
                                               const int* __restrict__ csr,
                                               const float* __restrict__ wa,
                                               const float* __restrict__ ba,
                                               const float* __restrict__ wb,
                                               const float* __restrict__ bb,
                                               const float* __restrict__ stPrev,
                                               const float* __restrict__ gammaPrev,
                                               const float* __restrict__ betaPrev,
                                               float* __restrict__ statsOut) {
    __shared__ float sWa[32 * 32];
    __shared__ float sWb[32 * 32];
    __shared__ float sBa[32], sBb[32];
    __shared__ float sSc[32], sSh[32];
    __shared__ float sStage[32 * SSTR];
    __shared__ float sSum[4 * 32], sSq[4 * 32];
    int tid = threadIdx.x;
    for (int i = tid; i < 32 * 32; i += 256) {
        sWb[i] = wb[i];
        if (MODE) sWa[i] = wa[i];
    }
    if (tid < 32) {
        sBa[tid] = ba[tid];
        sBb[tid] = bb[tid];
        if (MODE) {
            const float invn = 1.0f / NN;
            float mu = stPrev[tid] * invn;
            float var = stPrev[32 + tid] * invn - mu * mu;
            float scale = rsqrtf(var + BN_EPS) * gammaPrev[tid];
            sSc[tid] = scale;
            sSh[tid] = betaPrev[tid] - mu * scale;
        }
    }

    int l = tid & 3;
    int nl = tid >> 2;
    int node = blockIdx.x * 64 + nl;
    bool act = node < NN;

    // ---- gather phase (fp16 table, fp32 accum) ----
    int s = 0, e = 0;
    if (act) { s = rowptr[node]; e = rowptr[node + 1]; }
    const uint4* t4 = reinterpret_cast<const uint4*>(tblIn);
    float g[8];
#pragma unroll
    for (int c = 0; c < 8; c++) g[c] = 0.f;
    int i = s;
    for (; i + 4 <= e; i += 4) {
        int s0 = csr[i], s1 = csr[i + 1], s2 = csr[i + 2], s3 = csr[i + 3];
        uint4 w0 = t4[(long long)s0 * 4 + l];
        uint4 w1 = t4[(long long)s1 * 4 + l];
        uint4 w2 = t4[(long long)s2 * 4 + l];
        uint4 w3 = t4[(long long)s3 * 4 + l];
        float2 p;
        p = up2(w0.x); g[0] += p.x; g[1] += p.y;
        p = up2(w0.y); g[2] += p.x; g[3] += p.y;
        p = up2(w0.z); g[4] += p.x; g[5] += p.y;
        p = up2(w0.w); g[6] += p.x; g[7] += p.y;
        p = up2(w1.x); g[0] += p.x; g[1] += p.y;
        p = up2(w1.y); g[2] += p.x; g[3] += p.y;
        p = up2(w1.z); g[4] += p.x; g[5] += p.y;
        p = up2(w1.w); g[6] += p.x; g[7] += p.y;
        p = up2(w2.x); g[0] += p.x; g[1] += p.y;
        p = up2(w2.y); g[2] += p.x; g[3] += p.y;
        p = up2(w2.z); g[4] += p.x; g[5] += p.y;
        p = up2(w2.w); g[6] += p.x; g[7] += p.y;
        p = up2(w3.x); g[0] += p.x; g[1] += p.y;
        p = up2(w3.y); g[2] += p.x; g[3] += p.y;
        p = up2(w3.z); g[4] += p.x; g[5] += p.y;
        p = up2(w3.w); g[6] += p.x; g[7] += p.y;
    }
    for (; i < e; i++) {
        uint4 w = t4[(long long)csr[i] * 4 + l];
        float2 p;
        p = up2(w.x); g[0] += p.x; g[1] += p.y;
        p = up2(w.y); g[2] += p.x; g[3] += p.y;
        p = up2(w.z); g[4] += p.x; g[5] += p.y;
        p = up2(w.w); g[6] += p.x; g[7] += p.y;
    }
    __syncthreads();   // weights, biases, BN consts ready; gather done

    // ---- self-row + (BN) combine; stage GEMM input / t ----
    float t[8];
    if (MODE) {
        float in[8];
        if (act) {
            const float4* hr = reinterpret_cast<const float4*>(selfRow + (long long)node * 32 + l * 8);
            float4 h0 = hr[0], h1 = hr[1];
            float deg = (float)(e - s);
            float hv[8] = {h0.x, h0.y, h0.z, h0.w, h1.x, h1.y, h1.z, h1.w};
#pragma unroll
            for (int c = 0; c < 8; c++) {
                int f = l * 8 + c;
                in[c] = hv[c] * sSc[f] + sSh[f] + (g[c] * sSc[f] + deg * sSh[f]);
            }
        } else {
#pragma unroll
            for (int c = 0; c < 8; c++) in[c] = 0.f;
        }
#pragma unroll
        for (int c = 0; c < 8; c++) sStage[(l * 8 + c) * SSTR + nl] = in[c];
        __syncthreads();
        // GEMM1: t = relu(in @ Wa + ba)
#pragma unroll
        for (int j = 0; j < 8; j++) t[j] = sBa[l * 8 + j];
        const float4* w4a = reinterpret_cast<const float4*>(sWa);
#pragma unroll
        for (int k = 0; k < 32; k++) {
            float a = sStage[k * SSTR + nl];
            float4 w0 = w4a[k * 8 + 2 * l];
            float4 w1 = w4a[k * 8 + 2 * l + 1];
            t[0] += a * w0.x; t[1] += a * w0.y; t[2] += a * w0.z; t[3] += a * w0.w;
            t[4] += a * w1.x; t[5] += a * w1.y; t[6] += a * w1.z; t[7] += a * w1.w;
        }
#pragma unroll
        for (int j = 0; j < 8; j++) t[j] = fmaxf(t[j], 0.f);
        __syncthreads();   // all GEMM1 reads done before stage reuse
    } else {
        if (act) {
            const float4* yr = reinterpret_cast<const float4*>(selfRow + (long long)node * 32 + l * 8);
            float4 y0 = yr[0], y1 = yr[1];
            float yv[8] = {y0.x, y0.y, y0.z, y0.w, y1.x, y1.y, y1.z, y1.w};
#pragma unroll
            for (int c = 0; c < 8; c++) t[c] = fmaxf(yv[c] + g[c] + sBa[l * 8 + c], 0.f);
        } else {
#pragma unroll
            for (int c = 0; c < 8; c++) t[c] = 0.f;
        }
    }

    // ---- stage t; GEMM2: r = relu(t @ Wb + bb) ----
#pragma unroll
    for (int c = 0; c < 8; c++) sStage[(l * 8 + c) * SSTR + nl] = t[c];
    __syncthreads();
    float r[8];
#pragma unroll
    for (int j = 0; j < 8; j++) r[j] = sBb[l * 8 + j];
    const float4* w4b = reinterpret_cast<const float4*>(sWb);
#pragma unroll
    for (int k = 0; k < 32; k++) {
        float a = sStage[k * SSTR + nl];
        float4 w0 = w4b[k * 8 + 2 * l];
        float4 w1 = w4b[k * 8 + 2 * l + 1];
        r[0] += a * w0.x; r[1] += a * w0.y; r[2] += a * w0.z; r[3] += a * w0.w;
        r[4] += a * w1.x; r[5] += a * w1.y; r[6] += a * w1.z; r[7] += a * w1.w;
    }
#pragma unroll
    for (int j = 0; j < 8; j++) r[j] = fmaxf(r[j], 0.f);

    if (act) {
        float4* orow = reinterpret_cast<float4*>(hOut + (long long)node * 32 + l * 8);
        float4 o0, o1;
        o0.x = r[0]; o0.y = r[1]; o0.z = r[2]; o0.w = r[3];
        o1.x = r[4]; o1.y = r[5]; o1.z = r[6]; o1.w = r[7];
        orow[0] = o0; orow[1] = o1;
        uint4 p;
        p.x = pk2(r[0], r[1]); p.y = pk2(r[2], r[3]);
        p.z = pk2(r[4], r[5]); p.w = pk2(r[6], r[7]);
        reinterpret_cast<uint4*>(tblOut)[(long long)node * 4 + l] = p;
    } else {
#pragma unroll
        for (int j = 0; j < 8; j++) r[j] = 0.f;
    }

    // ---- stats: stride-4 wave reduce -> lanes 0..3 hold 8 feats each ----
    int lane = tid & 63, wid = tid >> 6;
#pragma unroll
    for (int j = 0; j < 8; j++) {
        float v = r[j], v2 = v * v;
        v += __shfl_down(v, 32, 64); v2 += __shfl_down(v2, 32, 64);
        v += __shfl_down(v, 16, 64); v2 += __shfl_down(v2, 16, 64);
        v += __shfl_down(v, 8, 64);  v2 += __shfl_down(v2, 8, 64);
        v += __shfl_down(v, 4, 64);  v2 += __shfl_down(v2, 4, 64);
        if (lane < 4) { sSum[wid * 32 + lane * 8 + j] = v; sSq[wid * 32 + lane * 8 + j] = v2; }
    }
    __syncthreads();
    if (tid < 32) {
        float a = sSum[tid] + sSum[32 + tid] + sSum[64 + tid] + sSum[96 + tid];
        float b = sSq[tid] + sSq[32 + tid] + sSq[64 + tid] + sSq[96 + tid];
        atomicAdd(&statsOut[tid], a);
        atomicAdd(&statsOut[32 + tid], b);
    }
}

// ============ pool with fused BN of layer 5, privatized atomics ============
#define POOL_NPB 512
__global__ __launch_bounds__(256) void pool_bn_k(const float* __restrict__ h,
                                                 const int* __restrict__ batch,
                                                 const float* __restrict__ st,
                                                 const float* __restrict__ gamma,
                                                 const float* __restrict__ beta,
                                                 float* __restrict__ pooled) {
    int tid = threadIdx.x;
    int f = tid & 31;
    int p = tid >> 5;
    int n0 = blockIdx.x * POOL_NPB + p * (POOL_NPB / 8);
    int n1 = n0 + POOL_NPB / 8;
    if (n1 > NN) n1 = NN;
    if (n0 >= NN) return;
    const float invn = 1.0f / NN;
    float mu = st[f] * invn;
    float var = st[32 + f] * invn - mu * mu;
    float sc = rsqrtf(var + BN_EPS) * gamma[f];
    float sh = beta[f] - mu * sc;
    float acc = 0.f;
    int cur = batch[n0];
    for (int n = n0; n < n1; n++) {
        int g = batch[n];
        if (g != cur) {
            atomicAdd(&pooled[cur * 32 + f], acc);
            cur = g;
            acc = 0.f;
        }
        acc += h[(long long)n * 32 + f] * sc + sh;
    }
    atomicAdd(&pooled[cur * 32 + f], acc);
}

// ============ final FCs ============
__global__ __launch_bounds__(64) void final_k(const float* __restrict__ pooled,
                                              const float* __restrict__ w1,
                                              const float* __restrict__ b1,
                                              const float* __restrict__ w2,
                                              const float* __restrict__ b2,
                                              float* __restrict__ out) {
    int g = threadIdx.x;
    if (g >= NG) return;
    float t[32];
#pragma unroll
    for (int j = 0; j < 32; j++) t[j] = b1[j];
    for (int k = 0; k < 32; k++) {
        float a = pooled[g * 32 + k];
#pragma unroll
        for (int j = 0; j < 32; j++) t[j] += a * w1[k * 32 + j];
    }
#pragma unroll
    for (int j = 0; j < 32; j++) t[j] = fmaxf(t[j], 0.f);
    for (int c = 0; c < NC; c++) {
        float o = b2[c];
#pragma unroll
        for (int k = 0; k < 32; k++) o += t[k] * w2[k * NC + c];
        out[g * NC + c] = o;
    }
}

extern "C" void kernel_launch(void* const* d_in, const int* in_sizes, int n_in,
                              void* d_out, int out_size, void* d_ws, size_t ws_size,
                              hipStream_t stream) {
    const float* x = (const float*)d_in[0];
    const int* ei = (const int*)d_in[1];
    const int* batch = (const int*)d_in[2];
    const float* w1a = (const float*)d_in[3];
    const float* b1a = (const float*)d_in[4];
    const float* w1b = (const float*)d_in[5];
    const float* b1b = (const float*)d_in[6];
    const float* Wa = (const float*)d_in[7];
    const float* Ba = (const float*)d_in[8];
    const float* Wb = (const float*)d_in[9];
    const float* Bb = (const float*)d_in[10];
    const float* bn_gamma = (const float*)d_in[11];
    const float* bn_beta = (const float*)d_in[12];
    const float* fc1w = (const float*)d_in[13];
    const float* fc1b = (const float*)d_in[14];
    const float* fc2w = (const float*)d_in[15];
    const float* fc2b = (const float*)d_in[16];
    float* out = (float*)d_out;

    float* ws = (float*)d_ws;
    float* y = ws;                                    // NN*32 f32
    float* hb = y + (size_t)NN * 32;                  // NN*32 f32
    float* stats_all = hb + (size_t)NN * 32;          // 5*64
    float* pooled = stats_all + 5 * 64;               // NG*32
    unsigned* yhf = (unsigned*)(pooled + NG * 32);    // NN*16 uints (32 fp16/row)
    unsigned* hfA = yhf + (size_t)NN * 16;            // NN*16
    unsigned* hfB = hfA + (size_t)NN * 16;            // NN*16
    unsigned* binned = hfB + (size_t)NN * 16;         // NE
    int* bcnt = (int*)(binned + NE);                  // NBUCK
    int* bbase = bcnt + NBUCK;                        // NBUCK+1
    int* bcur = bbase + NBUCK + 1;                    // NBUCK
    int* rowptr = bcur + NBUCK;                       // NN+1
    int* csr = rowptr + NN + 1;                       // NE

    const int nb4 = (NN + 63) / 64;   // 1563 blocks, 4 lanes/node

    // ---- CSR build (bucketed, packed) ----
    hipMemsetAsync(bcnt, 0, NBUCK * sizeof(int), stream);
    binA_k<<<NCH, 256, 0, stream>>>(ei, bcnt);
    binB_k<<<1, 512, 0, stream>>>(bcnt, bbase, bcur);
    binC_k<<<NCH, 256, 0, stream>>>(ei, bcur, binned);
    binD_k<<<NBUCK, 256, 0, stream>>>(binned, bbase, rowptr, csr);

    // ---- layer 1: y = x@W1a (+fp16 copy, zero stats/pooled); fused gather+tail ----
    pre1_k<<<nb4, 256, 0, stream>>>(x, w1a, y, yhf, stats_all);
    fused_k<0><<<nb4, 256, 0, stream>>>(y, hb, yhf, hfA, rowptr, csr,
                                        nullptr, b1a, w1b, b1b,
                                        nullptr, nullptr, nullptr, stats_all);

    // ---- layers 2-5: fused gather(BN-prev) + MLP; fp16 table ping-pong ----
    unsigned* tin = hfA;
    unsigned* tout = hfB;
    for (int i = 0; i < 4; i++) {
        fused_k<1><<<nb4, 256, 0, stream>>>(hb, hb, tin, tout, rowptr, csr,
                                            Wa + i * 1024, Ba + i * 32,
                                            Wb + i * 1024, Bb + i * 32,
                                            stats_all + i * 64, bn_gamma + i * 32,
                                            bn_beta + i * 32, stats_all + (i + 1) * 64);
        unsigned* tmp = tin; tin = tout; tout = tmp;
    }

    // ---- pool (BN5 fused) + FCs ----
    pool_bn_k<<<(NN + POOL_NPB - 1) / POOL_NPB, 256, 0, stream>>>(
        hb, batch, stats_all + 4 * 64, bn_gamma + 4 * 32, bn_beta + 4 * 32, pooled);
    final_k<<<1, 64, 0, stream>>>(pooled, fc1w, fc1b, fc2w, fc2b, out);
}

// Round 10
// 499.602 us; speedup vs baseline: 1.1689x; 1.0574x over previous
//
#include <hip/hip_runtime.h>
#include <hip/hip_fp16.h>

#define NN 100000
#define NE 1600000
#define NF 64
#define DM 32
#define NG 64
#define NC 10
#define BN_EPS 1e-5f

#define BSHIFT 8
#define NBUCK ((NN + 255) >> 8)        // 391 buckets of 256 nodes
#define CHUNK 8192                     // edges per binning block
#define NCH ((NE + CHUNK - 1) / CHUNK) // 196

// ---- fp16 pack/unpack helpers (RNE) ----
__device__ __forceinline__ float2 up2(unsigned u) {
    __half2 h = __builtin_bit_cast(__half2, u);
    return __half22float2(h);
}
__device__ __forceinline__ unsigned pk2(float a, float b) {
    __half2 h = __floats2half2_rn(a, b);
    return __builtin_bit_cast(unsigned, h);
}
__device__ __forceinline__ void acc8(float* a, uint4 w) {
    float2 p;
    p = up2(w.x); a[0] += p.x; a[1] += p.y;
    p = up2(w.y); a[2] += p.x; a[3] += p.y;
    p = up2(w.z); a[4] += p.x; a[5] += p.y;
    p = up2(w.w); a[6] += p.x; a[7] += p.y;
}

// ============ CSR build via bucket counting-sort ============
__global__ __launch_bounds__(256) void binA_k(const int* __restrict__ ei,
                                              int* __restrict__ bcnt) {
    __shared__ int h[NBUCK];
    for (int i = threadIdx.x; i < NBUCK; i += 256) h[i] = 0;
    __syncthreads();
    long long base = (long long)blockIdx.x * CHUNK;
    int n = (int)((NE - base < CHUNK) ? (NE - base) : CHUNK);
    for (int i = threadIdx.x; i < n; i += 256) {
        int d = ei[NE + base + i];
        atomicAdd(&h[d >> BSHIFT], 1);
    }
    __syncthreads();
    for (int i = threadIdx.x; i < NBUCK; i += 256)
        if (h[i]) atomicAdd(&bcnt[i], h[i]);
}

__global__ __launch_bounds__(512) void binB_k(const int* __restrict__ bcnt,
                                              int* __restrict__ bbase,
                                              int* __restrict__ bcur) {
    __shared__ int s[512];
    int t = threadIdx.x;
    int v = (t < NBUCK) ? bcnt[t] : 0;
    s[t] = v;
    __syncthreads();
    int acc = v;
    for (int off = 1; off < 512; off <<= 1) {
        int add = (t >= off) ? s[t - off] : 0;
        __syncthreads();
        acc += add;
        s[t] = acc;
        __syncthreads();
    }
    if (t < NBUCK) { bbase[t] = acc - v; bcur[t] = acc - v; }
    if (t == 0) bbase[NBUCK] = NE;
}

__global__ __launch_bounds__(256) void binC_k(const int* __restrict__ ei,
                                              int* __restrict__ bcur,
                                              unsigned* __restrict__ binned) {
    __shared__ int cnt[NBUCK];
    __shared__ int ofs[NBUCK];
    __shared__ int idx[NBUCK];
    for (int i = threadIdx.x; i < NBUCK; i += 256) { cnt[i] = 0; idx[i] = 0; }
    __syncthreads();
    long long base = (long long)blockIdx.x * CHUNK;
    int n = (int)((NE - base < CHUNK) ? (NE - base) : CHUNK);
    int d[CHUNK / 256];
#pragma unroll
    for (int k = 0; k < CHUNK / 256; k++) {
        int i = threadIdx.x + k * 256;
        int dd = (i < n) ? ei[NE + base + i] : -1;
        d[k] = dd;
        if (dd >= 0) atomicAdd(&cnt[dd >> BSHIFT], 1);
    }
    __syncthreads();
    for (int i = threadIdx.x; i < NBUCK; i += 256)
        if (cnt[i]) ofs[i] = atomicAdd(&bcur[i], cnt[i]);
    __syncthreads();
#pragma unroll
    for (int k = 0; k < CHUNK / 256; k++) {
        int i = threadIdx.x + k * 256;
        if (i < n) {
            unsigned src = (unsigned)ei[base + i];
            int b = d[k] >> BSHIFT;
            int l = atomicAdd(&idx[b], 1);
            binned[ofs[b] + l] = (src << 8) | (unsigned)(d[k] & 255);
        }
    }
}

__global__ __launch_bounds__(256) void binD_k(const unsigned* __restrict__ binned,
                                              const int* __restrict__ bbase,
                                              int* __restrict__ rowptr,
                                              int* __restrict__ csr) {
    __shared__ int cnt[256];
    __shared__ int cur[256];
    __shared__ int s[256];
    int b = blockIdx.x;
    int e0 = bbase[b], e1 = bbase[b + 1];
    int t = threadIdx.x;
    cnt[t] = 0;
    __syncthreads();
    for (int e = e0 + t; e < e1; e += 256) atomicAdd(&cnt[binned[e] & 255u], 1);
    __syncthreads();
    int v = cnt[t];
    s[t] = v;
    __syncthreads();
    int acc = v;
    for (int off = 1; off < 256; off <<= 1) {
        int add = (t >= off) ? s[t - off] : 0;
        __syncthreads();
        acc += add;
        s[t] = acc;
        __syncthreads();
    }
    int base = e0 + acc - v;
    int node = (b << BSHIFT) + t;
    if (node < NN) rowptr[node] = base;
    cur[t] = base;
    if (b == NBUCK - 1 && t == 0) rowptr[NN] = NE;
    __syncthreads();
    for (int e = e0 + t; e < e1; e += 256) {
        unsigned w = binned[e];
        int p = atomicAdd(&cur[w & 255u], 1);
        csr[p] = (int)(w >> 8);
    }
}

// ============ pre-pass layer 1: yhf = fp16(x @ W1a), 4 lanes/node; zero accumulators ============
__global__ __launch_bounds__(256) void pre1_k(const float* __restrict__ x,
                                              const float* __restrict__ wa,
                                              unsigned* __restrict__ yhf,
                                              float* __restrict__ zbuf) {
    __shared__ float sWa[64 * 32];
    int tid = threadIdx.x;
    if (blockIdx.x == 0) {
        for (int i = tid; i < 5 * 64 + NG * 32; i += 256) zbuf[i] = 0.f;
    }
    for (int i = tid; i < 64 * 32; i += 256) sWa[i] = wa[i];
    __syncthreads();
    int l = tid & 3;
    int node = blockIdx.x * 64 + (tid >> 2);
    if (node >= NN) return;
    float t[8];
#pragma unroll
    for (int j = 0; j < 8; j++) t[j] = 0.f;
    const float4* xr = reinterpret_cast<const float4*>(x + (long long)node * 64);
    const float4* w4 = reinterpret_cast<const float4*>(sWa);
#pragma unroll
    for (int k4 = 0; k4 < 16; k4++) {
        float4 xv = xr[k4];
        float av[4] = {xv.x, xv.y, xv.z, xv.w};
#pragma unroll
        for (int i = 0; i < 4; i++) {
            float a = av[i];
            float4 w0 = w4[(k4 * 4 + i) * 8 + 2 * l];
            float4 w1 = w4[(k4 * 4 + i) * 8 + 2 * l + 1];
            t[0] += a * w0.x; t[1] += a * w0.y; t[2] += a * w0.z; t[3] += a * w0.w;
            t[4] += a * w1.x; t[5] += a * w1.y; t[6] += a * w1.z; t[7] += a * w1.w;
        }
    }
    uint4 p;
    p.x = pk2(t[0], t[1]); p.y = pk2(t[2], t[3]);
    p.z = pk2(t[4], t[5]); p.w = pk2(t[6], t[7]);
    reinterpret_cast<uint4*>(yhf)[(long long)node * 4 + l] = p;
}

// ============ fused gather + MLP + BN-stats, 4 lanes/node, 64 nodes/block ============
// All inter-layer state lives in fp16 tables; self row read from tblIn.
// MODE 0: t = relu(self + gathersum + ba); r = relu(t@Wb + bb)
// MODE 1: in = BN(self) + (sc*gathersum + deg*sh); t = relu(in@Wa + ba); r = relu(t@Wb + bb)
#define SSTR 65
template <int MODE>
__global__ __launch_bounds__(256) void fused_k(const unsigned* __restrict__ tblIn,
                                               unsigned* __restrict__ tblOut,
                                               const int* __restrict__ rowptr,
                                               const int* __restrict__ csr,
                                               const float* __restrict__ wa,
                                               const float* __restrict__ ba,
                                               const float* __restrict__ wb,
                                               const float* __restrict__ bb,
                                               const float* __restrict__ stPrev,
                                               const float* __restrict__ gammaPrev,
                                               const float* __restrict__ betaPrev,
                                               float* __restrict__ statsOut) {
    __shared__ float sWa[32 * 32];
    __shared__ float sWb[32 * 32];
    __shared__ float sBa[32], sBb[32];
    __shared__ float sSc[32], sSh[32];
    __shared__ float sStage[32 * SSTR];
    __shared__ float sSum[4 * 32], sSq[4 * 32];
    int tid = threadIdx.x;
    for (int i = tid; i < 32 * 32; i += 256) {
        sWb[i] = wb[i];
        if (MODE) sWa[i] = wa[i];
    }
    if (tid < 32) {
        sBa[tid] = ba[tid];
        sBb[tid] = bb[tid];
        if (MODE) {
            const float invn = 1.0f / NN;
            float mu = stPrev[tid] * invn;
            float var = stPrev[32 + tid] * invn - mu * mu;
            float scale = rsqrtf(var + BN_EPS) * gammaPrev[tid];
            sSc[tid] = scale;
            sSh[tid] = betaPrev[tid] - mu * scale;
        }
    }

    int l = tid & 3;
    int nl = tid >> 2;
    int node = blockIdx.x * 64 + nl;
    bool act = node < NN;

    // ---- gather phase (fp16 table, fp32 accum), self row prefetched, unroll x8 ----
    int s = 0, e = 0;
    uint4 selfw = make_uint4(0, 0, 0, 0);
    const uint4* t4 = reinterpret_cast<const uint4*>(tblIn);
    if (act) {
        s = rowptr[node];
        e = rowptr[node + 1];
        selfw = t4[(long long)node * 4 + l];
    }
    float g[8];
#pragma unroll
    for (int c = 0; c < 8; c++) g[c] = 0.f;
    int i = s;
    for (; i + 8 <= e; i += 8) {
        int s0 = csr[i], s1 = csr[i + 1], s2 = csr[i + 2], s3 = csr[i + 3];
        int s4 = csr[i + 4], s5 = csr[i + 5], s6 = csr[i + 6], s7 = csr[i + 7];
        uint4 w0 = t4[(long long)s0 * 4 + l];
        uint4 w1 = t4[(long long)s1 * 4 + l];
        uint4 w2 = t4[(long long)s2 * 4 + l];
        uint4 w3 = t4[(long long)s3 * 4 + l];
        uint4 w4 = t4[(long long)s4 * 4 + l];
        uint4 w5 = t4[(long long)s5 * 4 + l];
        uint4 w6 = t4[(long long)s6 * 4 + l];
        uint4 w7 = t4[(long long)s7 * 4 + l];
        acc8(g, w0); acc8(g, w1); acc8(g, w2); acc8(g, w3);
        acc8(g, w4); acc8(g, w5); acc8(g, w6); acc8(g, w7);
    }
    if (i + 4 <= e) {
        int s0 = csr[i], s1 = csr[i + 1], s2 = csr[i + 2], s3 = csr[i + 3];
        uint4 w0 = t4[(long long)s0 * 4 + l];
        uint4 w1 = t4[(long long)s1 * 4 + l];
        uint4 w2 = t4[(long long)s2 * 4 + l];
        uint4 w3 = t4[(long long)s3 * 4 + l];
        acc8(g, w0); acc8(g, w1); acc8(g, w2); acc8(g, w3);
        i += 4;
    }
    for (; i < e; i++) {
        uint4 w = t4[(long long)csr[i] * 4 + l];
        acc8(g, w);
    }
    __syncthreads();   // weights, biases, BN consts ready; gather done

    // ---- self-row + (BN) combine; stage GEMM input / t ----
    float sv[8];
    {
        float2 p;
        p = up2(selfw.x); sv[0] = p.x; sv[1] = p.y;
        p = up2(selfw.y); sv[2] = p.x; sv[3] = p.y;
        p = up2(selfw.z); sv[4] = p.x; sv[5] = p.y;
        p = up2(selfw.w); sv[6] = p.x; sv[7] = p.y;
    }
    float t[8];
    if (MODE) {
        float in[8];
        if (act) {
            float deg = (float)(e - s);
#pragma unroll
            for (int c = 0; c < 8; c++) {
                int f = l * 8 + c;
                in[c] = sv[c] * sSc[f] + sSh[f] + (g[c] * sSc[f] + deg * sSh[f]);
            }
        } else {
#pragma unroll
            for (int c = 0; c < 8; c++) in[c] = 0.f;
        }
#pragma unroll
        for (int c = 0; c < 8; c++) sStage[(l * 8 + c) * SSTR + nl] = in[c];
        __syncthreads();
#pragma unroll
        for (int j = 0; j < 8; j++) t[j] = sBa[l * 8 + j];
        const float4* w4a = reinterpret_cast<const float4*>(sWa);
#pragma unroll
        for (int k = 0; k < 32; k++) {
            float a = sStage[k * SSTR + nl];
            float4 w0 = w4a[k * 8 + 2 * l];
            float4 w1 = w4a[k * 8 + 2 * l + 1];
            t[0] += a * w0.x; t[1] += a * w0.y; t[2] += a * w0.z; t[3] += a * w0.w;
            t[4] += a * w1.x; t[5] += a * w1.y; t[6] += a * w1.z; t[7] += a * w1.w;
        }
#pragma unroll
        for (int j = 0; j < 8; j++) t[j] = fmaxf(t[j], 0.f);
        __syncthreads();   // all GEMM1 reads done before stage reuse
    } else {
        if (act) {
#pragma unroll
            for (int c = 0; c < 8; c++) t[c] = fmaxf(sv[c] + g[c] + sBa[l * 8 + c], 0.f);
        } else {
#pragma unroll
            for (int c = 0; c < 8; c++) t[c] = 0.f;
        }
    }

    // ---- stage t; GEMM2: r = relu(t @ Wb + bb) ----
#pragma unroll
    for (int c = 0; c < 8; c++) sStage[(l * 8 + c) * SSTR + nl] = t[c];
    __syncthreads();
    float r[8];
#pragma unroll
    for (int j = 0; j < 8; j++) r[j] = sBb[l * 8 + j];
    const float4* w4b = reinterpret_cast<const float4*>(sWb);
#pragma unroll
    for (int k = 0; k < 32; k++) {
        float a = sStage[k * SSTR + nl];
        float4 w0 = w4b[k * 8 + 2 * l];
        float4 w1 = w4b[k * 8 + 2 * l + 1];
        r[0] += a * w0.x; r[1] += a * w0.y; r[2] += a * w0.z; r[3] += a * w0.w;
        r[4] += a * w1.x; r[5] += a * w1.y; r[6] += a * w1.z; r[7] += a * w1.w;
    }
#pragma unroll
    for (int j = 0; j < 8; j++) r[j] = fmaxf(r[j], 0.f);

    if (act) {
        uint4 p;
        p.x = pk2(r[0], r[1]); p.y = pk2(r[2], r[3]);
        p.z = pk2(r[4], r[5]); p.w = pk2(r[6], r[7]);
        reinterpret_cast<uint4*>(tblOut)[(long long)node * 4 + l] = p;
    } else {
#pragma unroll
        for (int j = 0; j < 8; j++) r[j] = 0.f;
    }

    // ---- stats: stride-4 wave reduce -> lanes 0..3 hold 8 feats each ----
    int lane = tid & 63, wid = tid >> 6;
#pragma unroll
    for (int j = 0; j < 8; j++) {
        float v = r[j], v2 = v * v;
        v += __shfl_down(v, 32, 64); v2 += __shfl_down(v2, 32, 64);
        v += __shfl_down(v, 16, 64); v2 += __shfl_down(v2, 16, 64);
        v += __shfl_down(v, 8, 64);  v2 += __shfl_down(v2, 8, 64);
        v += __shfl_down(v, 4, 64);  v2 += __shfl_down(v2, 4, 64);
        if (lane < 4) { sSum[wid * 32 + lane * 8 + j] = v; sSq[wid * 32 + lane * 8 + j] = v2; }
    }
    __syncthreads();
    if (tid < 32) {
        float a = sSum[tid] + sSum[32 + tid] + sSum[64 + tid] + sSum[96 + tid];
        float b = sSq[tid] + sSq[32 + tid] + sSq[64 + tid] + sSq[96 + tid];
        atomicAdd(&statsOut[tid], a);
        atomicAdd(&statsOut[32 + tid], b);
    }
}

// ============ pool (fp16 table) with fused BN of layer 5, privatized atomics ============
#define POOL_NPB 512
__global__ __launch_bounds__(256) void pool_bn_k(const unsigned* __restrict__ tbl,
                                                 const int* __restrict__ batch,
                                                 const float* __restrict__ st,
                                                 const float* __restrict__ gamma,
                                                 const float* __restrict__ beta,
                                                 float* __restrict__ pooled) {
    int tid = threadIdx.x;
    int f = tid & 31;
    int p = tid >> 5;
    int wrd = f >> 1;
    int hi = f & 1;
    int n0 = blockIdx.x * POOL_NPB + p * (POOL_NPB / 8);
    int n1 = n0 + POOL_NPB / 8;
    if (n1 > NN) n1 = NN;
    if (n0 >= NN) return;
    const float invn = 1.0f / NN;
    float mu = st[f] * invn;
    float var = st[32 + f] * invn - mu * mu;
    float sc = rsqrtf(var + BN_EPS) * gamma[f];
    float sh = beta[f] - mu * sc;
    float acc = 0.f;
    int cur = batch[n0];
    for (int n = n0; n < n1; n++) {
        int g = batch[n];
        if (g != cur) {
            atomicAdd(&pooled[cur * 32 + f], acc);
            cur = g;
            acc = 0.f;
        }
        float2 pv = up2(tbl[(long long)n * 16 + wrd]);
        acc += (hi ? pv.y : pv.x) * sc + sh;
    }
    atomicAdd(&pooled[cur * 32 + f], acc);
}

// ============ final FCs ============
__global__ __launch_bounds__(64) void final_k(const float* __restrict__ pooled,
                                              const float* __restrict__ w1,
                                              const float* __restrict__ b1,
                                              const float* __restrict__ w2,
                                              const float* __restrict__ b2,
                                              float* __restrict__ out) {
    int g = threadIdx.x;
    if (g >= NG) return;
    float t[32];
#pragma unroll
    for (int j = 0; j < 32; j++) t[j] = b1[j];
    for (int k = 0; k < 32; k++) {
        float a = pooled[g * 32 + k];
#pragma unroll
        for (int j = 0; j < 32; j++) t[j] += a * w1[k * 32 + j];
    }
#pragma unroll
    for (int j = 0; j < 32; j++) t[j] = fmaxf(t[j], 0.f);
    for (int c = 0; c < NC; c++) {
        float o = b2[c];
#pragma unroll
        for (int k = 0; k < 32; k++) o += t[k] * w2[k * NC + c];
        out[g * NC + c] = o;
    }
}

extern "C" void kernel_launch(void* const* d_in, const int* in_sizes, int n_in,
                              void* d_out, int out_size, void* d_ws, size_t ws_size,
                              hipStream_t stream) {
    const float* x = (const float*)d_in[0];
    const int* ei = (const int*)d_in[1];
    const int* batch = (const int*)d_in[2];
    const float* w1a = (const float*)d_in[3];
    const float* b1a = (const float*)d_in[4];
    const float* w1b = (const float*)d_in[5];
    const float* b1b = (const float*)d_in[6];
    const float* Wa = (const float*)d_in[7];
    const float* Ba = (const float*)d_in[8];
    const float* Wb = (const float*)d_in[9];
    const float* Bb = (const float*)d_in[10];
    const float* bn_gamma = (const float*)d_in[11];
    const float* bn_beta = (const float*)d_in[12];
    const float* fc1w = (const float*)d_in[13];
    const float* fc1b = (const float*)d_in[14];
    const float* fc2w = (const float*)d_in[15];
    const float* fc2b = (const float*)d_in[16];
    float* out = (float*)d_out;

    float* ws = (float*)d_ws;
    float* stats_all = ws;                            // 5*64
    float* pooled = stats_all + 5 * 64;               // NG*32
    unsigned* yhf = (unsigned*)(pooled + NG * 32);    // NN*16 uints (32 fp16/row)
    unsigned* hfA = yhf + (size_t)NN * 16;            // NN*16
    unsigned* hfB = hfA + (size_t)NN * 16;            // NN*16
    unsigned* binned = hfB + (size_t)NN * 16;         // NE
    int* bcnt = (int*)(binned + NE);                  // NBUCK
    int* bbase = bcnt + NBUCK;                        // NBUCK+1
    int* bcur = bbase + NBUCK + 1;                    // NBUCK
    int* rowptr = bcur + NBUCK;                       // NN+1
    int* csr = rowptr + NN + 1;                       // NE

    const int nb4 = (NN + 63) / 64;   // 1563 blocks, 4 lanes/node

    // ---- CSR build (bucketed, packed) ----
    hipMemsetAsync(bcnt, 0, NBUCK * sizeof(int), stream);
    binA_k<<<NCH, 256, 0, stream>>>(ei, bcnt);
    binB_k<<<1, 512, 0, stream>>>(bcnt, bbase, bcur);
    binC_k<<<NCH, 256, 0, stream>>>(ei, bcur, binned);
    binD_k<<<NBUCK, 256, 0, stream>>>(binned, bbase, rowptr, csr);

    // ---- layer 1: yhf = fp16(x@W1a) (+zero stats/pooled); fused gather+tail ----
    pre1_k<<<nb4, 256, 0, stream>>>(x, w1a, yhf, stats_all);
    fused_k<0><<<nb4, 256, 0, stream>>>(yhf, hfA, rowptr, csr,
                                        nullptr, b1a, w1b, b1b,
                                        nullptr, nullptr, nullptr, stats_all);

    // ---- layers 2-5: fused gather(BN-prev) + MLP; fp16 table ping-pong ----
    unsigned* tin = hfA;
    unsigned* tout = hfB;
    for (int i = 0; i < 4; i++) {
        fused_k<1><<<nb4, 256, 0, stream>>>(tin, tout, rowptr, csr,
                                            Wa + i * 1024, Ba + i * 32,
                                            Wb + i * 1024, Bb + i * 32,
                                            stats_all + i * 64, bn_gamma + i * 32,
                                            bn_beta + i * 32, stats_all + (i + 1) * 64);
        unsigned* tmp = tin; tin = tout; tout = tmp;
    }

    // ---- pool (BN5 fused, fp16 table) + FCs ----
    pool_bn_k<<<(NN + POOL_NPB - 1) / POOL_NPB, 256, 0, stream>>>(
        tin, batch, stats_all + 4 * 64, bn_gamma + 4 * 32, bn_beta + 4 * 32, pooled);
    final_k<<<1, 64, 0, stream>>>(pooled, fc1w, fc1b, fc2w, fc2b, out);
}